// Round 16
// baseline (82.561 us; speedup 1.0000x reference)
//
#include <hip/hip_runtime.h>
#include <math.h>
#include <stdint.h>

#define B_    16
#define CONDC 256
#define ICn   64
#define OCn   64
#define Hn    128
#define Wn    128
#define NW    36864
#define NPARAM 36928

typedef _Float16 half8 __attribute__((ext_vector_type(8)));
typedef _Float16 half4 __attribute__((ext_vector_type(4)));
typedef float f32x4 __attribute__((ext_vector_type(4)));
typedef float f32x16 __attribute__((ext_vector_type(16)));

__device__ inline unsigned pk2(float a, float b) {
    union { _Float16 h[2]; unsigned u; } q;
    q.h[0] = (_Float16)a; q.h[1] = (_Float16)b;
    return q.u;
}

// ===================== COND-GEMM (R8 exact): wt[b][icq][tap][oc][ic16] f16 + bias =====================
__global__ __launch_bounds__(256, 4) void gemm_k(const float* __restrict__ cond,
                                                 const float* __restrict__ Wc,
                                                 const float* __restrict__ bc,
                                                 _Float16* __restrict__ wt,
                                                 float* __restrict__ bias) {
    __shared__ _Float16 wl[64 * 280];          // 35840 B
    const int tid = threadIdx.x;
    const int pbase = blockIdx.x * 64;

    float4 v[16];
    #pragma unroll
    for (int t = 0; t < 16; ++t) {
        int u = t * 256 + tid;
        int pl = u >> 6, kg = u & 63;
        v[t] = *((const float4*)(Wc + (size_t)(pbase + pl) * 256) + kg);
    }
    __builtin_amdgcn_sched_barrier(0);

    #pragma unroll
    for (int t = 0; t < 16; ++t) {
        int u = t * 256 + tid;
        int pl = u >> 6, kg = u & 63;
        half4 h = { (_Float16)v[t].x, (_Float16)v[t].y, (_Float16)v[t].z, (_Float16)v[t].w };
        *(half4*)(wl + pl * 280 + kg * 4) = h;
    }
    __syncthreads();

    const int w = tid >> 6, l = tid & 63, n = l & 15, r4 = l >> 4;
    const _Float16* arow = wl + (w * 16 + n) * 280 + r4 * 8;
    const float*    crow = cond + n * 256 + r4 * 8;
    f32x4 acc = (f32x4){0.f, 0.f, 0.f, 0.f};
    #pragma unroll
    for (int kk = 0; kk < 8; ++kk) {
        half8 av = *(const half8*)(arow + kk * 32);
        float4 u0 = *(const float4*)(crow + kk * 32);
        float4 u1 = *(const float4*)(crow + kk * 32 + 4);
        half8 bv;
        bv[0] = (_Float16)u0.x; bv[1] = (_Float16)u0.y; bv[2] = (_Float16)u0.z; bv[3] = (_Float16)u0.w;
        bv[4] = (_Float16)u1.x; bv[5] = (_Float16)u1.y; bv[6] = (_Float16)u1.z; bv[7] = (_Float16)u1.w;
        acc = __builtin_amdgcn_mfma_f32_16x16x32_f16(av, bv, acc, 0, 0, 0);
    }
    #pragma unroll
    for (int j = 0; j < 4; ++j) {
        int p = pbase + w * 16 + r4 * 4 + j;   // C/D: col=lane&15 (batch), row=(lane>>4)*4+j
        float vv = tanhf(acc[j] + bc[p]) * 5.0f;
        if (p < NW) {
            int oc = p / 576, rem = p - oc * 576;
            int ic = rem / 9,  t  = rem - ic * 9;
            int icq = ic >> 4, icl = ic & 15;
            wt[((((size_t)n * 4 + icq) * 9 + t) * 64 + oc) * 16 + icl] = (_Float16)vv;
        } else {
            bias[n * 64 + (p - NW)] = vv;
        }
    }
}

// ===================== CONV FUSED: raw-x staging (transpose eliminated), v5 sync skeleton =====================
// 1024 blocks (XCD-swizzled). Block: 32px x 8rows x 64oc; 4 waves = ot(2) x rg(2).
// LDS slice = [16 ic][10 rows][40 x] f32 = 25600 B; 3 buffers = 76800 B (2 blocks/CU).
// Staging: clamped source addresses; OOB handled by predicate-zero at fragment assembly.
// STAGE = 7 vm-ops/wave (6 full + 1 16-lane tail); LOADA = 9. Ladder (in-order): 23,16,9,0.
__global__ __launch_bounds__(256, 2) void conv_fused(const float* __restrict__ x,
                                                     const _Float16* __restrict__ wt,
                                                     const float* __restrict__ bias,
                                                     float* __restrict__ out) {
    __shared__ float xs[3 * 6400];             // 76800 B
    const int tid = threadIdx.x;
    const int l   = tid & 63;
    const int w   = tid >> 6;
    const int px  = l & 31;
    const int jj  = l >> 5;
    const int ot  = w & 1;
    const int rg  = w >> 1;

    // bijective XCD swizzle: 1024 % 8 == 0
    const int sw = (blockIdx.x & 7) * 128 + (blockIdx.x >> 3);
    const int Xt = sw & 3, Yt = (sw >> 2) & 15, b = sw >> 6;
    const int X0 = Xt * 32;
    const int Y0 = Yt * 8;                     // raw top output row

    const float*    xbat = x  + (size_t)b * 1048576;
    const _Float16* wbat = wt + (size_t)b * 36864 + (size_t)(ot * 32 + px) * 16 + jj * 8;
    const int Lb = rg * 4;

    // ---- stage slice ICQ into buffer BUF: 1600 chunks (16 ic x 10 rows x 10 xchunks) ----
    #define GLOADF(SRC, OFF)                                                            \
        __builtin_amdgcn_global_load_lds(                                               \
            (const __attribute__((address_space(1))) void*)(SRC),                       \
            (__attribute__((address_space(3))) void*)((__attribute__((address_space(3))) char*)xs + (OFF)), \
            16, 0, 0)

    #define STAGEQ(ICQ, BUF) do {                                                       \
        _Pragma("unroll")                                                               \
        for (int it = 0; it < 6; ++it) {                                                \
            int d   = it * 256 + tid;                                                   \
            int icd = (int)((unsigned)d / 100u);                                        \
            int rem = d - icd * 100;                                                    \
            int rr  = (int)((unsigned)rem / 10u);                                       \
            int c   = rem - rr * 10;                                                    \
            int ry  = Y0 - 1 + rr; ry = ry < 0 ? 0 : (ry > 127 ? 127 : ry);             \
            int xst = X0 - 4 + 4 * c; xst = xst < 0 ? 0 : (xst > 124 ? 124 : xst);      \
            const float* src = xbat + (size_t)((ICQ) * 16 + icd) * 16384 + ry * 128 + xst; \
            GLOADF(src, (BUF) * 25600 + (it * 256 + (tid & ~63)) * 16);                 \
        }                                                                               \
        {   /* tail: 64 chunks, 16 lanes per wave -> uniform 7 vm-ops/wave */           \
            int d   = 1536 + w * 16 + (l & 15);                                         \
            int icd = (int)((unsigned)d / 100u);                                        \
            int rem = d - icd * 100;                                                    \
            int rr  = (int)((unsigned)rem / 10u);                                       \
            int c   = rem - rr * 10;                                                    \
            int ry  = Y0 - 1 + rr; ry = ry < 0 ? 0 : (ry > 127 ? 127 : ry);             \
            int xst = X0 - 4 + 4 * c; xst = xst < 0 ? 0 : (xst > 124 ? 124 : xst);      \
            const float* src = xbat + (size_t)((ICQ) * 16 + icd) * 16384 + ry * 128 + xst; \
            if (l < 16)                                                                 \
                GLOADF(src, (BUF) * 25600 + (1536 + w * 16) * 16);                      \
        } } while (0)

    #define LOADA(AIDX, ICQ) do {                                                       \
        _Pragma("unroll")                                                               \
        for (int t = 0; t < 9; ++t)                                                     \
            A[AIDX][t] = *(const half8*)(wbat + (size_t)((ICQ) * 9 + t) * 1024);        \
        } while (0)

    // fragment assembly from f32 LDS with predicate-zero halo; then MFMA (pure LDS+reg)
    #define COMPUTE(AIDX, BUF) do {                                                     \
        const float* bufb = (const float*)((const char*)xs + (BUF) * 25600);            \
        __builtin_amdgcn_s_setprio(1);                                                  \
        _Pragma("unroll")                                                               \
        for (int kw = 0; kw < 3; ++kw) {                                                \
            const int gx = X0 + px + kw - 1;                                            \
            const bool xOK = (gx >= 0) && (gx <= 127);                                  \
            half8 Bf[6];                                                                \
            _Pragma("unroll")                                                           \
            for (int iy = 0; iy < 6; ++iy) {                                            \
                const int rr  = Lb + iy;                                                \
                const int ry  = Y0 - 1 + rr;                                            \
                const bool ok = xOK && (ry >= 0) && (ry <= 127);                        \
                const float* sp = bufb + jj * 3200 + rr * 40 + (px + kw + 3);           \
                half8 h;                                                                \
                _Pragma("unroll")                                                       \
                for (int e = 0; e < 8; ++e) {                                           \
                    float fv = ok ? sp[e * 400] : 0.0f;                                 \
                    h[e] = (_Float16)fv;                                                \
                }                                                                       \
                Bf[iy] = h;                                                             \
            }                                                                           \
            _Pragma("unroll")                                                           \
            for (int iy = 0; iy < 6; ++iy) {                                            \
                _Pragma("unroll")                                                       \
                for (int kh = 0; kh < 3; ++kh) {                                        \
                    const int r = iy - kh;                                              \
                    if (r >= 0 && r < 4)                                                \
                        acc[r] = __builtin_amdgcn_mfma_f32_32x32x16_f16(A[AIDX][kh * 3 + kw], Bf[iy], acc[r], 0, 0, 0); \
                } } }                                                                   \
        __builtin_amdgcn_s_setprio(0);                                                  \
    } while (0)

    half8 A[2][9];
    f32x16 acc[4];
    #pragma unroll
    for (int r = 0; r < 4; ++r) acc[r] = (f32x16){};

    // ---- prologue: A0(9) S0(7) S1(7) S2(7) ----
    LOADA(0, 0);
    __builtin_amdgcn_sched_barrier(0);
    STAGEQ(0, 0); STAGEQ(1, 1); STAGEQ(2, 2);
    __builtin_amdgcn_sched_barrier(0);

    // ---- i0: A1(9); drain A0+S0 -> remaining S1,S2,A1 = 23 ----
    LOADA(1, 1);
    __builtin_amdgcn_sched_barrier(0);
    asm volatile("s_waitcnt vmcnt(23)" ::: "memory");
    __builtin_amdgcn_sched_barrier(0);
    __builtin_amdgcn_s_barrier();
    __builtin_amdgcn_sched_barrier(0);
    COMPUTE(0, 0);
    asm volatile("s_waitcnt lgkmcnt(0)" ::: "memory");
    __builtin_amdgcn_sched_barrier(0);
    __builtin_amdgcn_s_barrier();              // buf0 free for re-stage
    __builtin_amdgcn_sched_barrier(0);
    STAGEQ(3, 0);
    __builtin_amdgcn_sched_barrier(0);

    // ---- i1: A2(9); drain S1,S2,A1 -> remaining S3,A2 = 16 ----
    LOADA(0, 2);
    __builtin_amdgcn_sched_barrier(0);
    asm volatile("s_waitcnt vmcnt(16)" ::: "memory");
    __builtin_amdgcn_sched_barrier(0);
    __builtin_amdgcn_s_barrier();
    __builtin_amdgcn_sched_barrier(0);
    COMPUTE(1, 1);

    // ---- i2: A3(9); drain S3,A2 -> remaining A3 = 9 ----
    LOADA(1, 3);
    __builtin_amdgcn_sched_barrier(0);
    asm volatile("s_waitcnt vmcnt(9)" ::: "memory");
    __builtin_amdgcn_sched_barrier(0);
    __builtin_amdgcn_s_barrier();
    __builtin_amdgcn_sched_barrier(0);
    COMPUTE(0, 2);

    // ---- i3: drain all ----
    asm volatile("s_waitcnt vmcnt(0)" ::: "memory");
    __builtin_amdgcn_sched_barrier(0);
    __builtin_amdgcn_s_barrier();
    __builtin_amdgcn_sched_barrier(0);
    COMPUTE(1, 0);

    #undef STAGEQ
    #undef LOADA
    #undef COMPUTE
    #undef GLOADF

    // ---- epilogue: D col = lane&31 = px, oc-within-32 = (reg&3)+8*(reg>>2)+4*jj ----
    const float* bb = bias + b * 64;
    #pragma unroll
    for (int r = 0; r < 4; ++r) {
        const int yo = Y0 + Lb + r;
        float* ob = out + (((size_t)(b * 64 + ot * 32)) * 128 + yo) * 128 + X0 + px;
        #pragma unroll
        for (int reg = 0; reg < 16; ++reg) {
            const int ocl = (reg & 3) + 8 * (reg >> 2) + 4 * jj;
            ob[(size_t)ocl * 16384] = acc[r][reg] + bb[ot * 32 + ocl];
        }
    }
}

// ===================== FALLBACK (fp32 direct, R1) =====================
__global__ __launch_bounds__(256) void cond_gemm(const float* __restrict__ cond,
                                                 const float* __restrict__ Wc,
                                                 const float* __restrict__ bc,
                                                 float* __restrict__ wb) {
    __shared__ float condl[B_][CONDC + 1];
    __shared__ float Wl[16][CONDC + 1];
    const int tid = threadIdx.x;
    const int p0 = blockIdx.x * 16;
    for (int i = tid; i < B_ * CONDC; i += 256) condl[i >> 8][i & 255] = cond[i];
    for (int i = tid; i < 16 * CONDC; i += 256) {
        int pl = i >> 8, k = i & 255;
        Wl[pl][k] = Wc[(p0 + pl) * CONDC + k];
    }
    __syncthreads();
    const int pl = tid >> 4;
    const int b  = tid & 15;
    float acc = bc[p0 + pl];
    #pragma unroll 8
    for (int k = 0; k < CONDC; ++k) acc += Wl[pl][k] * condl[b][k];
    wb[b * NPARAM + p0 + pl] = tanhf(acc) * 5.0f;
}

#define TS  32
#define OG  8
#define ICC 8
__global__ __launch_bounds__(256) void conv_kernel(const float* __restrict__ x,
                                                   const float* __restrict__ wb,
                                                   float* __restrict__ out) {
    __shared__ float fxs[ICC][TS + 2][TS + 2];
    __shared__ float ws[OG][ICC][9];
    const int tid = threadIdx.x;
    const int b   = blockIdx.z;
    const int ocg = blockIdx.y * OG;
    const int tx0 = (blockIdx.x & 3) * TS;
    const int ty0 = (blockIdx.x >> 2) * TS;
    const int px  = (tid & 15) * 2;
    const int py  = (tid >> 4) * 2;
    float acc[OG][4];
    #pragma unroll
    for (int o = 0; o < OG; ++o)
        #pragma unroll
        for (int q = 0; q < 4; ++q) acc[o][q] = 0.0f;
    const float* wbase = wb + b * NPARAM;
    for (int ic0 = 0; ic0 < ICn; ic0 += ICC) {
        for (int i = tid; i < ICC * (TS + 2) * (TS + 2); i += 256) {
            int icl = i / ((TS + 2) * (TS + 2));
            int rem = i % ((TS + 2) * (TS + 2));
            int yy = rem / (TS + 2), xx = rem % (TS + 2);
            int gy = ty0 - 1 + yy, gx = tx0 - 1 + xx;
            float v = 0.0f;
            if (gy >= 0 && gy < Hn && gx >= 0 && gx < Wn)
                v = x[((b * ICn + ic0 + icl) * Hn + gy) * Wn + gx];
            fxs[icl][yy][xx] = v;
        }
        for (int i = tid; i < OG * ICC * 9; i += 256) {
            int o = i / (ICC * 9), rem = i % (ICC * 9);
            int icl = rem / 9, k = rem % 9;
            ws[o][icl][k] = wbase[((ocg + o) * ICn + ic0 + icl) * 9 + k];
        }
        __syncthreads();
        #pragma unroll
        for (int icl = 0; icl < ICC; ++icl) {
            float xv[4][4];
            #pragma unroll
            for (int dy = 0; dy < 4; ++dy)
                #pragma unroll
                for (int dx = 0; dx < 4; ++dx) xv[dy][dx] = fxs[icl][py + dy][px + dx];
            #pragma unroll
            for (int o = 0; o < OG; ++o)
                #pragma unroll
                for (int kh = 0; kh < 3; ++kh)
                    #pragma unroll
                    for (int kw = 0; kw < 3; ++kw) {
                        float wv = ws[o][icl][kh * 3 + kw];
                        acc[o][0] += xv[kh][kw] * wv;
                        acc[o][1] += xv[kh][kw + 1] * wv;
                        acc[o][2] += xv[kh + 1][kw] * wv;
                        acc[o][3] += xv[kh + 1][kw + 1] * wv;
                    }
        }
        __syncthreads();
    }
    #pragma unroll
    for (int o = 0; o < OG; ++o) {
        float bias = wbase[NW + ocg + o];
        int oc = ocg + o;
        float* obase = out + ((size_t)(b * OCn + oc) * Hn + (ty0 + py)) * Wn + tx0 + px;
        obase[0] = acc[o][0] + bias;
        obase[1] = acc[o][1] + bias;
        obase[Wn] = acc[o][2] + bias;
        obase[Wn + 1] = acc[o][3] + bias;
    }
}

// ===================== LAUNCH =====================
extern "C" void kernel_launch(void* const* d_in, const int* in_sizes, int n_in,
                              void* d_out, int out_size, void* d_ws, size_t ws_size,
                              hipStream_t stream) {
    const float* x    = (const float*)d_in[0];
    const float* cond = (const float*)d_in[1];
    const float* Wc   = (const float*)d_in[2];
    const float* bc   = (const float*)d_in[3];
    float* out = (float*)d_out;

    const size_t WT_BYTES = (size_t)B_ * 9 * 64 * 64 * 2;            // 1179648
    const size_t BIAS_OFF = WT_BYTES;
    const size_t NEED     = WT_BYTES + 64 * B_ * sizeof(float);

    if (ws_size >= NEED) {
        _Float16* wt   = (_Float16*)d_ws;
        float*    bias = (float*)((char*)d_ws + BIAS_OFF);
        gemm_k<<<dim3(577), 256, 0, stream>>>(cond, Wc, bc, wt, bias);
        conv_fused<<<dim3(1024), 256, 0, stream>>>(x, wt, bias, out);
    } else {
        float* wbuf = (float*)d_ws;
        cond_gemm<<<dim3(NPARAM / 16), 256, 0, stream>>>(cond, Wc, bc, wbuf);
        conv_kernel<<<dim3(16, OCn / OG, B_), 256, 0, stream>>>(x, wbuf, out);
    }
}